// Round 2
// baseline (1231.567 us; speedup 1.0000x reference)
//
#include <hip/hip_runtime.h>
#include <hip/hip_bf16.h>
#include <cstdint>
#include <cstddef>

#define D 256

// ---------------- CSR build ----------------

__global__ __launch_bounds__(256) void k_deg(const int* __restrict__ dst,
                                             int* __restrict__ deg, int E) {
  int e = blockIdx.x * 256 + threadIdx.x;
  if (e < E) atomicAdd(&deg[dst[e]], 1);
}

__global__ __launch_bounds__(1024) void k_scan(const int* __restrict__ deg,
                                               int* __restrict__ row_ptr,
                                               int* __restrict__ cursor, int n) {
  __shared__ int sm[1024];
  __shared__ int s_carry;
  int tid = threadIdx.x;
  if (tid == 0) s_carry = 0;
  __syncthreads();
  int nchunks = (n + 1023) / 1024;
  for (int c = 0; c < nchunks; ++c) {
    int i = c * 1024 + tid;
    int v = (i < n) ? deg[i] : 0;
    sm[tid] = v;
    __syncthreads();
    for (int off = 1; off < 1024; off <<= 1) {
      int t = (tid >= off) ? sm[tid - off] : 0;
      __syncthreads();
      sm[tid] += t;
      __syncthreads();
    }
    int carry = s_carry;          // all threads read old carry
    int excl = sm[tid] - v + carry;
    if (i < n) { row_ptr[i] = excl; cursor[i] = excl; }
    int total = carry + sm[1023];
    __syncthreads();              // ensure reads of s_carry done before update
    if (tid == 0) s_carry = total;
    __syncthreads();
  }
  if (tid == 0) row_ptr[n] = s_carry;
}

__global__ __launch_bounds__(256) void k_fill(const int* __restrict__ src,
                                              const int* __restrict__ dst,
                                              int* __restrict__ cursor,
                                              int* __restrict__ col, int E) {
  int e = blockIdx.x * 256 + threadIdx.x;
  if (e < E) {
    int p = atomicAdd(&cursor[dst[e]], 1);
    col[p] = src[e];
  }
}

// ---------------- fp32 tiled GEMM: C = A[M,256] @ W[256,256]^T (+bias)(+relu) ----------------

__global__ __launch_bounds__(256) void k_gemm(const float* __restrict__ A,
                                              const float* __restrict__ W,
                                              const float* __restrict__ bias,
                                              float* __restrict__ C,
                                              int M, int relu) {
  __shared__ float As[16][68];  // [k][m], stride 68 floats = 272 B (16B aligned)
  __shared__ float Bs[16][68];  // [k][n]
  int tid = threadIdx.x;
  int by = blockIdx.x;  // m block (64 rows)
  int bx = blockIdx.y;  // n block (64 cols, 0..3)
  int tx = tid & 15, ty = tid >> 4;
  int lrow = tid >> 2;           // 0..63
  int lk4 = (tid & 3) << 2;      // 0,4,8,12
  int arow = by * 64 + lrow;
  int bn = bx * 64 + lrow;
  const float4 zero4 = make_float4(0.f, 0.f, 0.f, 0.f);
  float acc[4][4] = {};

  for (int k0 = 0; k0 < 256; k0 += 16) {
    float4 av = (arow < M) ? *(const float4*)(A + (size_t)arow * D + k0 + lk4) : zero4;
    float4 bv = *(const float4*)(W + (size_t)bn * D + k0 + lk4);
    __syncthreads();
    As[lk4 + 0][lrow] = av.x; As[lk4 + 1][lrow] = av.y;
    As[lk4 + 2][lrow] = av.z; As[lk4 + 3][lrow] = av.w;
    Bs[lk4 + 0][lrow] = bv.x; Bs[lk4 + 1][lrow] = bv.y;
    Bs[lk4 + 2][lrow] = bv.z; Bs[lk4 + 3][lrow] = bv.w;
    __syncthreads();
#pragma unroll
    for (int kk = 0; kk < 16; ++kk) {
      float4 a = *(const float4*)&As[kk][ty * 4];
      float4 b = *(const float4*)&Bs[kk][tx * 4];
      float ar[4] = {a.x, a.y, a.z, a.w};
      float br[4] = {b.x, b.y, b.z, b.w};
#pragma unroll
      for (int i = 0; i < 4; ++i)
#pragma unroll
        for (int j = 0; j < 4; ++j)
          acc[i][j] += ar[i] * br[j];
    }
  }

  float4 b4 = bias ? *(const float4*)(bias + bx * 64 + tx * 4) : zero4;
  float bb[4] = {b4.x, b4.y, b4.z, b4.w};
#pragma unroll
  for (int i = 0; i < 4; ++i) {
    int m = by * 64 + ty * 4 + i;
    if (m < M) {
      float4 v;
      v.x = acc[i][0] + bb[0];
      v.y = acc[i][1] + bb[1];
      v.z = acc[i][2] + bb[2];
      v.w = acc[i][3] + bb[3];
      if (relu) {
        v.x = fmaxf(v.x, 0.f); v.y = fmaxf(v.y, 0.f);
        v.z = fmaxf(v.z, 0.f); v.w = fmaxf(v.w, 0.f);
      }
      *(float4*)(C + (size_t)m * D + bx * 64 + tx * 4) = v;
    }
  }
}

// ---------------- aggregation: T2[n] = relu(mean_{j in N(n)} T1[col[j]] + T2[n]) ----------------

__global__ __launch_bounds__(256) void k_agg(const float* __restrict__ T1,
                                             float* __restrict__ T2,
                                             const int* __restrict__ row_ptr,
                                             const int* __restrict__ col) {
  int n = blockIdx.x;
  int t = threadIdx.x;
  int beg = row_ptr[n], end = row_ptr[n + 1];
  float sum = 0.f;
  for (int j = beg; j < end; ++j) {
    int s = col[j];
    sum += T1[(size_t)s * D + t];
  }
  int degn = end - beg;
  float inv = 1.0f / (float)(degn > 0 ? degn : 1);
  size_t idx = (size_t)n * D + t;
  float v = sum * inv + T2[idx];
  T2[idx] = fmaxf(v, 0.f);
}

// ---------------- final: out = softmax(H[M,256] @ Wm2[8,256]^T + bm2) ----------------

__global__ __launch_bounds__(256) void k_final(const float* __restrict__ H,
                                               const float* __restrict__ Wm2,
                                               const float* __restrict__ bm2,
                                               float* __restrict__ out, int M) {
  int node = blockIdx.x * 4 + (threadIdx.x >> 6);
  int lane = threadIdx.x & 63;
  if (node >= M) return;
  int o = lane >> 3;   // 0..7 output index
  int r = lane & 7;    // 0..7 k-slice
  const float* h = H + (size_t)node * D;
  const float* w = Wm2 + (size_t)o * D;
  float p = 0.f;
  for (int k = r; k < D; k += 8) p += h[k] * w[k];
  p += __shfl_xor(p, 1);
  p += __shfl_xor(p, 2);
  p += __shfl_xor(p, 4);
  float logit = p + bm2[o];   // all 8 lanes of o-group hold logit_o
  float m = logit;
  m = fmaxf(m, __shfl_xor(m, 8));
  m = fmaxf(m, __shfl_xor(m, 16));
  m = fmaxf(m, __shfl_xor(m, 32));
  float e = expf(logit - m);
  float s = e;
  s += __shfl_xor(s, 8);
  s += __shfl_xor(s, 16);
  s += __shfl_xor(s, 32);
  if (r == 0) out[(size_t)node * 8 + o] = e / s;
}

// ---------------- launch ----------------

extern "C" void kernel_launch(void* const* d_in, const int* in_sizes, int n_in,
                              void* d_out, int out_size, void* d_ws, size_t ws_size,
                              hipStream_t stream) {
  const float* x   = (const float*)d_in[0];
  const int*   ei  = (const int*)d_in[1];
  const float* W1l = (const float*)d_in[2];
  const float* b1  = (const float*)d_in[3];
  const float* W1r = (const float*)d_in[4];
  const float* W2l = (const float*)d_in[5];
  const float* b2  = (const float*)d_in[6];
  const float* W2r = (const float*)d_in[7];
  const float* Wm1 = (const float*)d_in[8];
  const float* bm1 = (const float*)d_in[9];
  const float* Wm2 = (const float*)d_in[10];
  const float* bm2 = (const float*)d_in[11];
  float* out = (float*)d_out;

  int M = in_sizes[0] / D;      // 50000
  int E = in_sizes[1] / 2;      // 800000
  const int* src = ei;
  const int* dst = ei + E;

  float* bufA = (float*)d_ws;
  float* bufB = bufA + (size_t)M * D;
  float* bufC = bufB + (size_t)M * D;
  int* deg     = (int*)(bufC + (size_t)M * D);
  int* row_ptr = deg + M;
  int* cursor  = row_ptr + (M + 1);
  int* col     = cursor + M;

  hipMemsetAsync(deg, 0, (size_t)M * sizeof(int), stream);
  k_deg<<<dim3((E + 255) / 256), dim3(256), 0, stream>>>(dst, deg, E);
  k_scan<<<dim3(1), dim3(1024), 0, stream>>>(deg, row_ptr, cursor, M);
  k_fill<<<dim3((E + 255) / 256), dim3(256), 0, stream>>>(src, dst, cursor, col, E);

  dim3 g((M + 63) / 64, 4);
  // Layer 1: T1 = x@W1l^T -> bufA ; T2 = x@W1r^T + b1 -> bufB ; h1 = relu(mean(T1)+T2) in bufB
  k_gemm<<<g, dim3(256), 0, stream>>>(x, W1l, nullptr, bufA, M, 0);
  k_gemm<<<g, dim3(256), 0, stream>>>(x, W1r, b1, bufB, M, 0);
  k_agg<<<dim3(M), dim3(256), 0, stream>>>(bufA, bufB, row_ptr, col);
  // Layer 2: T3 = h1@W2l^T -> bufA ; T4 = h1@W2r^T + b2 -> bufC ; h2 = relu(mean(T3)+T4) in bufC
  k_gemm<<<g, dim3(256), 0, stream>>>(bufB, W2l, nullptr, bufA, M, 0);
  k_gemm<<<g, dim3(256), 0, stream>>>(bufB, W2r, b2, bufC, M, 0);
  k_agg<<<dim3(M), dim3(256), 0, stream>>>(bufA, bufC, row_ptr, col);
  // MLP: h3 = relu(h2@Wm1^T + bm1) -> bufA
  k_gemm<<<g, dim3(256), 0, stream>>>(bufC, Wm1, bm1, bufA, M, 1);
  // logits + softmax
  k_final<<<dim3((M + 3) / 4), dim3(256), 0, stream>>>(bufA, Wm2, bm2, out, M);
}

// Round 3
// 737.913 us; speedup vs baseline: 1.6690x; 1.6690x over previous
//
#include <hip/hip_runtime.h>
#include <hip/hip_bf16.h>
#include <cstdint>
#include <cstddef>

#define D 256

typedef __attribute__((ext_vector_type(8))) short bf16x8;
typedef __attribute__((ext_vector_type(4))) float f32x4;
typedef __attribute__((ext_vector_type(4))) unsigned short ushort4v;

__device__ __forceinline__ unsigned short f2bf(float f) {  // RNE
  union { float f; unsigned int u; } v; v.f = f;
  unsigned int u = v.u;
  u += ((u >> 16) & 1u) + 0x7fffu;
  return (unsigned short)(u >> 16);
}
__device__ __forceinline__ float bf2f(unsigned short s) {
  union { unsigned int u; float f; } v; v.u = ((unsigned int)s) << 16;
  return v.f;
}

#define GLL16(g, l) __builtin_amdgcn_global_load_lds( \
    (const __attribute__((address_space(1))) void*)(g), \
    (__attribute__((address_space(3))) void*)(l), 16, 0, 0)

// ---------------- CSR build ----------------

__global__ __launch_bounds__(256) void k_deg(const int* __restrict__ dst,
                                             int* __restrict__ deg, int E) {
  int e = blockIdx.x * 256 + threadIdx.x;
  if (e < E) atomicAdd(&deg[dst[e]], 1);
}

__global__ __launch_bounds__(1024) void k_scan(const int* __restrict__ deg,
                                               int* __restrict__ row_ptr,
                                               int* __restrict__ cursor, int n) {
  __shared__ int sm[1024];
  __shared__ int s_carry;
  int tid = threadIdx.x;
  if (tid == 0) s_carry = 0;
  __syncthreads();
  int nchunks = (n + 1023) / 1024;
  for (int c = 0; c < nchunks; ++c) {
    int i = c * 1024 + tid;
    int v = (i < n) ? deg[i] : 0;
    sm[tid] = v;
    __syncthreads();
    for (int off = 1; off < 1024; off <<= 1) {
      int t = (tid >= off) ? sm[tid - off] : 0;
      __syncthreads();
      sm[tid] += t;
      __syncthreads();
    }
    int carry = s_carry;
    int excl = sm[tid] - v + carry;
    if (i < n) { row_ptr[i] = excl; cursor[i] = excl; }
    int total = carry + sm[1023];
    __syncthreads();
    if (tid == 0) s_carry = total;
    __syncthreads();
  }
  if (tid == 0) row_ptr[n] = s_carry;
}

__global__ __launch_bounds__(256) void k_fill(const int* __restrict__ src,
                                              const int* __restrict__ dst,
                                              int* __restrict__ cursor,
                                              int* __restrict__ col, int E) {
  int e = blockIdx.x * 256 + threadIdx.x;
  if (e < E) {
    int p = atomicAdd(&cursor[dst[e]], 1);
    col[p] = src[e];
  }
}

// ---------------- fp32 -> split bf16 (hi, lo) ----------------

__global__ __launch_bounds__(256) void k_split(const float* __restrict__ in,
                                               unsigned short* __restrict__ oh,
                                               unsigned short* __restrict__ ol,
                                               int n4) {
  int i = blockIdx.x * 256 + threadIdx.x;
  if (i >= n4) return;
  float4 v = ((const float4*)in)[i];
  float a[4] = {v.x, v.y, v.z, v.w};
  ushort4v h, l;
#pragma unroll
  for (int j = 0; j < 4; ++j) {
    h[j] = f2bf(a[j]);
    l[j] = f2bf(a[j] - bf2f(h[j]));
  }
  ((ushort4v*)oh)[i] = h;
  ((ushort4v*)ol)[i] = l;
}

// ---------------- split-bf16 MFMA GEMM ----------------
// C[M, NBF+NF] = (Ah+Al)[M,256] @ (Wh+Wl)[NBF+NF,256]^T  (3-term split product)
// cols < NBF  -> bf16 store to outBF (stride NBF)
// cols >= NBF -> f32 store (+bias, optional relu) to outF32 (stride NF)
// Tile 128x128, BK=32, 256 threads (4 waves, 2x2 of 64x64 each).

__global__ __launch_bounds__(256) void k_gemm_mfma(
    const unsigned short* __restrict__ Ah, const unsigned short* __restrict__ Al,
    const unsigned short* __restrict__ Wh, const unsigned short* __restrict__ Wl,
    unsigned short* __restrict__ outBF, float* __restrict__ outF32,
    const float* __restrict__ bias, int M, int NBF, int NF, int relu) {
  __shared__ char lds[32768];
  char* tA_h = lds;
  char* tA_l = lds + 8192;
  char* tW_h = lds + 16384;
  char* tW_l = lds + 24576;

  const int tid = threadIdx.x;
  const int wave = tid >> 6;
  const int lane = tid & 63;
  const int by = blockIdx.x, bx = blockIdx.y;
  const int n0 = bx * 128;

  // staging: linear LDS dest (base + lane*16), global source pre-permuted
  // so that a read at logical k-slot g uses physical slot g ^ ((row>>1)&3).
  int aoff[2], woff[2], ldso[2];
#pragma unroll
  for (int r = 0; r < 2; ++r) {
    int o = r * 4096 + wave * 1024 + lane * 16;  // byte offset in tile
    int row = o >> 6;                             // 64 B per row (32 bf16)
    int sp = (o >> 4) & 3;                        // physical 16B slot
    int sl = sp ^ ((row >> 1) & 3);               // logical k-slot stored here
    int arow = by * 128 + row; if (arow > M - 1) arow = M - 1;
    aoff[r] = arow * 256 + sl * 8;                // elements
    woff[r] = (n0 + row) * 256 + sl * 8;
    ldso[r] = r * 4096 + wave * 1024;             // wave-uniform LDS base
  }

  const int rbase = (wave >> 1) * 64;
  const int cbase = (wave & 1) * 64;
  const int fr = lane & 15;
  const int g = lane >> 4;

  int a_addr[4], w_addr[4];
#pragma unroll
  for (int m = 0; m < 4; ++m) {
    int row = rbase + m * 16 + fr;
    a_addr[m] = row * 64 + ((g ^ ((row >> 1) & 3)) * 16);
  }
#pragma unroll
  for (int n = 0; n < 4; ++n) {
    int row = cbase + n * 16 + fr;
    w_addr[n] = row * 64 + ((g ^ ((row >> 1) & 3)) * 16);
  }

  f32x4 acc[4][4] = {};

  for (int k0 = 0; k0 < 256; k0 += 32) {
    __syncthreads();
#pragma unroll
    for (int r = 0; r < 2; ++r) {
      GLL16(Ah + aoff[r] + k0, tA_h + ldso[r]);
      GLL16(Al + aoff[r] + k0, tA_l + ldso[r]);
      GLL16(Wh + woff[r] + k0, tW_h + ldso[r]);
      GLL16(Wl + woff[r] + k0, tW_l + ldso[r]);
    }
    __syncthreads();
    bf16x8 ah[4], al[4], wh[4], wl[4];
#pragma unroll
    for (int m = 0; m < 4; ++m) {
      ah[m] = *(const bf16x8*)(tA_h + a_addr[m]);
      al[m] = *(const bf16x8*)(tA_l + a_addr[m]);
    }
#pragma unroll
    for (int n = 0; n < 4; ++n) {
      wh[n] = *(const bf16x8*)(tW_h + w_addr[n]);
      wl[n] = *(const bf16x8*)(tW_l + w_addr[n]);
    }
#pragma unroll
    for (int m = 0; m < 4; ++m)
#pragma unroll
      for (int n = 0; n < 4; ++n) {
        acc[m][n] = __builtin_amdgcn_mfma_f32_16x16x32_bf16(ah[m], wh[n], acc[m][n], 0, 0, 0);
        acc[m][n] = __builtin_amdgcn_mfma_f32_16x16x32_bf16(ah[m], wl[n], acc[m][n], 0, 0, 0);
        acc[m][n] = __builtin_amdgcn_mfma_f32_16x16x32_bf16(al[m], wh[n], acc[m][n], 0, 0, 0);
      }
  }

  // epilogue: C/D layout col=lane&15, row=(lane>>4)*4+reg
#pragma unroll
  for (int n = 0; n < 4; ++n) {
    int col = n0 + cbase + n * 16 + fr;
    bool isbf = col < NBF;
    int fcol = col - NBF;
    float bv = (!isbf && bias) ? bias[fcol] : 0.f;
#pragma unroll
    for (int m = 0; m < 4; ++m) {
      f32x4 a = acc[m][n];
#pragma unroll
      for (int r = 0; r < 4; ++r) {
        int row = by * 128 + rbase + m * 16 + g * 4 + r;
        if (row < M) {
          if (isbf) {
            outBF[(size_t)row * NBF + col] = f2bf(a[r]);
          } else {
            float v = a[r] + bv;
            if (relu) v = fmaxf(v, 0.f);
            outF32[(size_t)row * NF + fcol] = v;
          }
        }
      }
    }
  }
}

// ---------------- aggregation ----------------
// one wave per node: h = relu(mean_gather(T1_bf16) + T2_f32); write split bf16

__global__ __launch_bounds__(256) void k_agg2(const unsigned short* __restrict__ T1,
                                              const float* __restrict__ T2,
                                              unsigned short* __restrict__ Hh,
                                              unsigned short* __restrict__ Hl,
                                              const int* __restrict__ row_ptr,
                                              const int* __restrict__ col, int M) {
  int wave = threadIdx.x >> 6, lane = threadIdx.x & 63;
  int n = blockIdx.x * 4 + wave;
  if (n >= M) return;
  int beg = row_ptr[n], end = row_ptr[n + 1];
  float s0 = 0.f, s1 = 0.f, s2 = 0.f, s3 = 0.f;
  for (int j = beg; j < end; ++j) {
    int src = col[j];
    ushort4v t = *(const ushort4v*)(T1 + (size_t)src * 256 + lane * 4);
    s0 += bf2f(t[0]); s1 += bf2f(t[1]); s2 += bf2f(t[2]); s3 += bf2f(t[3]);
  }
  int dg = end - beg;
  float inv = 1.0f / (float)(dg > 0 ? dg : 1);
  float4 t2 = *(const float4*)(T2 + (size_t)n * 256 + lane * 4);
  float h[4];
  h[0] = fmaxf(s0 * inv + t2.x, 0.f);
  h[1] = fmaxf(s1 * inv + t2.y, 0.f);
  h[2] = fmaxf(s2 * inv + t2.z, 0.f);
  h[3] = fmaxf(s3 * inv + t2.w, 0.f);
  ushort4v hh, hl;
#pragma unroll
  for (int i = 0; i < 4; ++i) {
    hh[i] = f2bf(h[i]);
    hl[i] = f2bf(h[i] - bf2f(hh[i]));
  }
  *(ushort4v*)(Hh + (size_t)n * 256 + lane * 4) = hh;
  *(ushort4v*)(Hl + (size_t)n * 256 + lane * 4) = hl;
}

// ---------------- final: out = softmax(H[M,256] @ Wm2[8,256]^T + bm2) ----------------

__global__ __launch_bounds__(256) void k_final(const float* __restrict__ H,
                                               const float* __restrict__ Wm2,
                                               const float* __restrict__ bm2,
                                               float* __restrict__ out, int M) {
  int node = blockIdx.x * 4 + (threadIdx.x >> 6);
  int lane = threadIdx.x & 63;
  if (node >= M) return;
  int o = lane >> 3;
  int r = lane & 7;
  const float* h = H + (size_t)node * D;
  const float* w = Wm2 + (size_t)o * D;
  float p = 0.f;
  for (int k = r; k < D; k += 8) p += h[k] * w[k];
  p += __shfl_xor(p, 1);
  p += __shfl_xor(p, 2);
  p += __shfl_xor(p, 4);
  float logit = p + bm2[o];
  float m = logit;
  m = fmaxf(m, __shfl_xor(m, 8));
  m = fmaxf(m, __shfl_xor(m, 16));
  m = fmaxf(m, __shfl_xor(m, 32));
  float e = expf(logit - m);
  float s = e;
  s += __shfl_xor(s, 8);
  s += __shfl_xor(s, 16);
  s += __shfl_xor(s, 32);
  if (r == 0) out[(size_t)node * 8 + o] = e / s;
}

// ---------------- launch ----------------

extern "C" void kernel_launch(void* const* d_in, const int* in_sizes, int n_in,
                              void* d_out, int out_size, void* d_ws, size_t ws_size,
                              hipStream_t stream) {
  const float* x   = (const float*)d_in[0];
  const int*   ei  = (const int*)d_in[1];
  const float* W1l = (const float*)d_in[2];
  const float* b1  = (const float*)d_in[3];
  const float* W1r = (const float*)d_in[4];
  const float* W2l = (const float*)d_in[5];
  const float* b2  = (const float*)d_in[6];
  const float* W2r = (const float*)d_in[7];
  const float* Wm1 = (const float*)d_in[8];
  const float* bm1 = (const float*)d_in[9];
  const float* Wm2 = (const float*)d_in[10];
  const float* bm2 = (const float*)d_in[11];
  float* out = (float*)d_out;

  int M = in_sizes[0] / D;   // 50000
  int E = in_sizes[1] / 2;   // 800000
  const int* src = ei;
  const int* dst = ei + E;

  char* p = (char*)d_ws;
  auto alloc = [&](size_t bytes) {
    char* q = p;
    p += (bytes + 255) & ~(size_t)255;
    return q;
  };
  unsigned short* bh0  = (unsigned short*)alloc((size_t)M * 256 * 2);  // x/h split hi
  unsigned short* bh1  = (unsigned short*)alloc((size_t)M * 256 * 2);  // x/h split lo
  unsigned short* T1bf = (unsigned short*)alloc((size_t)M * 256 * 2);  // neighbor-path (bf16)
  float*          T2f  = (float*)alloc((size_t)M * 256 * 4);           // root-path / mlp out (f32)
  unsigned short* Wc1h = (unsigned short*)alloc(512 * 256 * 2);
  unsigned short* Wc1l = (unsigned short*)alloc(512 * 256 * 2);
  unsigned short* Wc2h = (unsigned short*)alloc(512 * 256 * 2);
  unsigned short* Wc2l = (unsigned short*)alloc(512 * 256 * 2);
  unsigned short* Wm1h = (unsigned short*)alloc(256 * 256 * 2);
  unsigned short* Wm1l = (unsigned short*)alloc(256 * 256 * 2);
  int* deg     = (int*)alloc((size_t)M * 4);
  int* row_ptr = (int*)alloc((size_t)(M + 1) * 4);
  int* cursor  = (int*)alloc((size_t)M * 4);
  int* col     = (int*)alloc((size_t)E * 4);

  // CSR build
  hipMemsetAsync(deg, 0, (size_t)M * sizeof(int), stream);
  k_deg<<<dim3((E + 255) / 256), dim3(256), 0, stream>>>(dst, deg, E);
  k_scan<<<dim3(1), dim3(1024), 0, stream>>>(deg, row_ptr, cursor, M);
  k_fill<<<dim3((E + 255) / 256), dim3(256), 0, stream>>>(src, dst, cursor, col, E);

  // split conversions
  int nx4 = M * 256 / 4;
  k_split<<<dim3((nx4 + 255) / 256), dim3(256), 0, stream>>>(x, bh0, bh1, nx4);
  int nw4 = 256 * 256 / 4;
  k_split<<<dim3((nw4 + 255) / 256), dim3(256), 0, stream>>>(W1l, Wc1h, Wc1l, nw4);
  k_split<<<dim3((nw4 + 255) / 256), dim3(256), 0, stream>>>(W1r, Wc1h + 65536, Wc1l + 65536, nw4);
  k_split<<<dim3((nw4 + 255) / 256), dim3(256), 0, stream>>>(W2l, Wc2h, Wc2l, nw4);
  k_split<<<dim3((nw4 + 255) / 256), dim3(256), 0, stream>>>(W2r, Wc2h + 65536, Wc2l + 65536, nw4);
  k_split<<<dim3((nw4 + 255) / 256), dim3(256), 0, stream>>>(Wm1, Wm1h, Wm1l, nw4);

  dim3 blk(256);
  dim3 g4((M + 127) / 128, 4);
  dim3 g2((M + 127) / 128, 2);
  int aggGrid = (M + 3) / 4;

  // Layer 1: [T1 | T2] = x @ [W1l;W1r]^T ; T2 += b1 ; h1 = relu(mean(T1)+T2) -> split into bh0/bh1
  k_gemm_mfma<<<g4, blk, 0, stream>>>(bh0, bh1, Wc1h, Wc1l, T1bf, T2f, b1, M, 256, 256, 0);
  k_agg2<<<dim3(aggGrid), blk, 0, stream>>>(T1bf, T2f, bh0, bh1, row_ptr, col, M);
  // Layer 2
  k_gemm_mfma<<<g4, blk, 0, stream>>>(bh0, bh1, Wc2h, Wc2l, T1bf, T2f, b2, M, 256, 256, 0);
  k_agg2<<<dim3(aggGrid), blk, 0, stream>>>(T1bf, T2f, bh0, bh1, row_ptr, col, M);
  // MLP layer 1: h3 = relu(h2 @ Wm1^T + bm1) -> T2f
  k_gemm_mfma<<<g2, blk, 0, stream>>>(bh0, bh1, Wm1h, Wm1l, nullptr, T2f, bm1, M, 0, 256, 1);
  // logits + softmax
  k_final<<<dim3((M + 3) / 4), blk, 0, stream>>>(T2f, Wm2, bm2, out, M);
}

// Round 4
// 605.634 us; speedup vs baseline: 2.0335x; 1.2184x over previous
//
#include <hip/hip_runtime.h>
#include <hip/hip_bf16.h>
#include <cstdint>
#include <cstddef>

#define D 256

typedef __attribute__((ext_vector_type(8))) short bf16x8;
typedef __attribute__((ext_vector_type(4))) float f32x4;
typedef __attribute__((ext_vector_type(4))) unsigned short ushort4v;
typedef __attribute__((ext_vector_type(8))) unsigned short ushort8v;

__device__ __forceinline__ unsigned short f2bf(float f) {  // RNE
  union { float f; unsigned int u; } v; v.f = f;
  unsigned int u = v.u;
  u += ((u >> 16) & 1u) + 0x7fffu;
  return (unsigned short)(u >> 16);
}
__device__ __forceinline__ float bf2f(unsigned short s) {
  union { unsigned int u; float f; } v; v.u = ((unsigned int)s) << 16;
  return v.f;
}

#define GLL16(g, l) __builtin_amdgcn_global_load_lds( \
    (const __attribute__((address_space(1))) void*)(g), \
    (__attribute__((address_space(3))) void*)(l), 16, 0, 0)

// ---------------- CSR build ----------------

__global__ __launch_bounds__(256) void k_deg(const int* __restrict__ dst,
                                             int* __restrict__ deg, int E) {
  int e = blockIdx.x * 256 + threadIdx.x;
  if (e < E) atomicAdd(&deg[dst[e]], 1);
}

// block partial sums: each block sums 1024 degs
__global__ __launch_bounds__(256) void k_bsum(const int* __restrict__ deg,
                                              int* __restrict__ bsum, int M) {
  __shared__ int sm[256];
  int tid = threadIdx.x;
  int base = blockIdx.x * 1024 + tid * 4;
  int s = 0;
#pragma unroll
  for (int i = 0; i < 4; ++i) s += (base + i < M) ? deg[base + i] : 0;
  sm[tid] = s;
  __syncthreads();
  for (int off = 128; off > 0; off >>= 1) {
    if (tid < off) sm[tid] += sm[tid + off];
    __syncthreads();
  }
  if (tid == 0) bsum[blockIdx.x] = sm[0];
}

// single-wave prefix over nb (<=64) block sums; also writes row_ptr[M] = total
__global__ __launch_bounds__(64) void k_scanb(const int* __restrict__ bsum,
                                              int* __restrict__ boff,
                                              int* __restrict__ row_ptr,
                                              int nb, int M) {
  int l = threadIdx.x;
  int orig = (l < nb) ? bsum[l] : 0;
  int v = orig;
  for (int off = 1; off < 64; off <<= 1) {
    int t = __shfl_up(v, off);
    if (l >= off) v += t;
  }
  if (l < nb) boff[l] = v - orig;      // exclusive prefix
  if (l == nb - 1) row_ptr[M] = v;     // total edge count
}

// apply: block-wide exclusive scan of 1024 degs + block offset
__global__ __launch_bounds__(256) void k_apply(const int* __restrict__ deg,
                                               const int* __restrict__ boff,
                                               int* __restrict__ row_ptr,
                                               int* __restrict__ cursor, int M) {
  __shared__ int sm[256];
  int tid = threadIdx.x;
  int base = blockIdx.x * 1024 + tid * 4;
  int d[4], p[4];
#pragma unroll
  for (int i = 0; i < 4; ++i) d[i] = (base + i < M) ? deg[base + i] : 0;
  p[0] = 0; p[1] = d[0]; p[2] = d[0] + d[1]; p[3] = d[0] + d[1] + d[2];
  int s = p[3] + d[3];
  sm[tid] = s;
  __syncthreads();
  for (int off = 1; off < 256; off <<= 1) {
    int t = (tid >= off) ? sm[tid - off] : 0;
    __syncthreads();
    sm[tid] += t;
    __syncthreads();
  }
  int excl = sm[tid] - s + boff[blockIdx.x];
#pragma unroll
  for (int i = 0; i < 4; ++i) {
    if (base + i < M) {
      row_ptr[base + i] = excl + p[i];
      cursor[base + i] = excl + p[i];
    }
  }
}

__global__ __launch_bounds__(256) void k_fill(const int* __restrict__ src,
                                              const int* __restrict__ dst,
                                              int* __restrict__ cursor,
                                              int* __restrict__ col, int E) {
  int e = blockIdx.x * 256 + threadIdx.x;
  if (e < E) {
    int p = atomicAdd(&cursor[dst[e]], 1);
    col[p] = src[e];
  }
}

// ---------------- fp32 -> split bf16 (hi, lo) ----------------

__global__ __launch_bounds__(256) void k_split(const float* __restrict__ in,
                                               unsigned short* __restrict__ oh,
                                               unsigned short* __restrict__ ol,
                                               int n4) {
  int i = blockIdx.x * 256 + threadIdx.x;
  if (i >= n4) return;
  float4 v = ((const float4*)in)[i];
  float a[4] = {v.x, v.y, v.z, v.w};
  ushort4v h, l;
#pragma unroll
  for (int j = 0; j < 4; ++j) {
    h[j] = f2bf(a[j]);
    l[j] = f2bf(a[j] - bf2f(h[j]));
  }
  ((ushort4v*)oh)[i] = h;
  ((ushort4v*)ol)[i] = l;
}

// ---------------- split-bf16 MFMA GEMM ----------------
// C[M, NBF+NF] = (Ah+Al)[M,256] @ (Wh+Wl)[NBF+NF,256]^T  (3-term split product)
// cols < NBF  -> bf16 store to outBF (stride NBF)
// cols >= NBF -> f32 store (+bias, optional relu) to outF32 (stride NF)
// Tile 128x128, BK=32, 256 threads (4 waves, 2x2 of 64x64 each).

__global__ __launch_bounds__(256) void k_gemm_mfma(
    const unsigned short* __restrict__ Ah, const unsigned short* __restrict__ Al,
    const unsigned short* __restrict__ Wh, const unsigned short* __restrict__ Wl,
    unsigned short* __restrict__ outBF, float* __restrict__ outF32,
    const float* __restrict__ bias, int M, int NBF, int NF, int relu) {
  __shared__ char lds[32768];
  char* tA_h = lds;
  char* tA_l = lds + 8192;
  char* tW_h = lds + 16384;
  char* tW_l = lds + 24576;

  const int tid = threadIdx.x;
  const int wave = tid >> 6;
  const int lane = tid & 63;
  const int by = blockIdx.x, bx = blockIdx.y;
  const int n0 = bx * 128;

  // staging: linear LDS dest (base + lane*16), global source pre-permuted
  // so that a read at logical k-slot g uses physical slot g ^ ((row>>1)&3).
  int aoff[2], woff[2], ldso[2];
#pragma unroll
  for (int r = 0; r < 2; ++r) {
    int o = r * 4096 + wave * 1024 + lane * 16;  // byte offset in tile
    int row = o >> 6;                             // 64 B per row (32 bf16)
    int sp = (o >> 4) & 3;                        // physical 16B slot
    int sl = sp ^ ((row >> 1) & 3);               // logical k-slot stored here
    int arow = by * 128 + row; if (arow > M - 1) arow = M - 1;
    aoff[r] = arow * 256 + sl * 8;                // elements
    woff[r] = (n0 + row) * 256 + sl * 8;
    ldso[r] = r * 4096 + wave * 1024;             // wave-uniform LDS base
  }

  const int rbase = (wave >> 1) * 64;
  const int cbase = (wave & 1) * 64;
  const int fr = lane & 15;
  const int g = lane >> 4;

  int a_addr[4], w_addr[4];
#pragma unroll
  for (int m = 0; m < 4; ++m) {
    int row = rbase + m * 16 + fr;
    a_addr[m] = row * 64 + ((g ^ ((row >> 1) & 3)) * 16);
  }
#pragma unroll
  for (int n = 0; n < 4; ++n) {
    int row = cbase + n * 16 + fr;
    w_addr[n] = row * 64 + ((g ^ ((row >> 1) & 3)) * 16);
  }

  f32x4 acc[4][4] = {};

  for (int k0 = 0; k0 < 256; k0 += 32) {
    __syncthreads();
#pragma unroll
    for (int r = 0; r < 2; ++r) {
      GLL16(Ah + aoff[r] + k0, tA_h + ldso[r]);
      GLL16(Al + aoff[r] + k0, tA_l + ldso[r]);
      GLL16(Wh + woff[r] + k0, tW_h + ldso[r]);
      GLL16(Wl + woff[r] + k0, tW_l + ldso[r]);
    }
    __syncthreads();
    bf16x8 ah[4], al[4], wh[4], wl[4];
#pragma unroll
    for (int m = 0; m < 4; ++m) {
      ah[m] = *(const bf16x8*)(tA_h + a_addr[m]);
      al[m] = *(const bf16x8*)(tA_l + a_addr[m]);
    }
#pragma unroll
    for (int n = 0; n < 4; ++n) {
      wh[n] = *(const bf16x8*)(tW_h + w_addr[n]);
      wl[n] = *(const bf16x8*)(tW_l + w_addr[n]);
    }
#pragma unroll
    for (int m = 0; m < 4; ++m)
#pragma unroll
      for (int n = 0; n < 4; ++n) {
        acc[m][n] = __builtin_amdgcn_mfma_f32_16x16x32_bf16(ah[m], wh[n], acc[m][n], 0, 0, 0);
        acc[m][n] = __builtin_amdgcn_mfma_f32_16x16x32_bf16(ah[m], wl[n], acc[m][n], 0, 0, 0);
        acc[m][n] = __builtin_amdgcn_mfma_f32_16x16x32_bf16(al[m], wh[n], acc[m][n], 0, 0, 0);
      }
  }

  // epilogue: C/D layout col=lane&15, row=(lane>>4)*4+reg
#pragma unroll
  for (int n = 0; n < 4; ++n) {
    int col = n0 + cbase + n * 16 + fr;
    bool isbf = col < NBF;
    int fcol = col - NBF;
    float bv = (!isbf && bias) ? bias[fcol] : 0.f;
#pragma unroll
    for (int m = 0; m < 4; ++m) {
      f32x4 a = acc[m][n];
#pragma unroll
      for (int r = 0; r < 4; ++r) {
        int row = by * 128 + rbase + m * 16 + g * 4 + r;
        if (row < M) {
          if (isbf) {
            outBF[(size_t)row * NBF + col] = f2bf(a[r]);
          } else {
            float v = a[r] + bv;
            if (relu) v = fmaxf(v, 0.f);
            outF32[(size_t)row * NF + fcol] = v;
          }
        }
      }
    }
  }
}

// ---------------- aggregation ----------------
// one wave per node, 2 edges per iteration (16B loads):
// lanes 0-31 -> edge j, lanes 32-63 -> edge j+1; combine via shfl_xor(32).
// h = relu(mean_gather(T1_bf16) + T2_f32); write split bf16 (hi by half 0, lo by half 1)

__global__ __launch_bounds__(256) void k_agg2(const unsigned short* __restrict__ T1,
                                              const float* __restrict__ T2,
                                              unsigned short* __restrict__ Hh,
                                              unsigned short* __restrict__ Hl,
                                              const int* __restrict__ row_ptr,
                                              const int* __restrict__ col, int M) {
  int wave = threadIdx.x >> 6, lane = threadIdx.x & 63;
  int n = blockIdx.x * 4 + wave;
  if (n >= M) return;
  int beg = row_ptr[n], end = row_ptr[n + 1];
  int half = lane >> 5, sl = lane & 31;
  float s[8] = {0.f, 0.f, 0.f, 0.f, 0.f, 0.f, 0.f, 0.f};
  for (int j = beg + half; j < end; j += 2) {
    int srcr = col[j];
    ushort8v v = *(const ushort8v*)(T1 + (size_t)srcr * 256 + sl * 8);
#pragma unroll
    for (int i = 0; i < 8; ++i) s[i] += bf2f(v[i]);
  }
#pragma unroll
  for (int i = 0; i < 8; ++i) s[i] += __shfl_xor(s[i], 32);
  int dg = end - beg;
  float inv = 1.0f / (float)(dg > 0 ? dg : 1);
  const float4* t2p = (const float4*)(T2 + (size_t)n * 256 + sl * 8);
  float4 ta = t2p[0], tb = t2p[1];
  float h[8];
  h[0] = fmaxf(s[0] * inv + ta.x, 0.f);
  h[1] = fmaxf(s[1] * inv + ta.y, 0.f);
  h[2] = fmaxf(s[2] * inv + ta.z, 0.f);
  h[3] = fmaxf(s[3] * inv + ta.w, 0.f);
  h[4] = fmaxf(s[4] * inv + tb.x, 0.f);
  h[5] = fmaxf(s[5] * inv + tb.y, 0.f);
  h[6] = fmaxf(s[6] * inv + tb.z, 0.f);
  h[7] = fmaxf(s[7] * inv + tb.w, 0.f);
  if (half == 0) {
    ushort8v hh;
#pragma unroll
    for (int i = 0; i < 8; ++i) hh[i] = f2bf(h[i]);
    *(ushort8v*)(Hh + (size_t)n * 256 + sl * 8) = hh;
  } else {
    ushort8v hl;
#pragma unroll
    for (int i = 0; i < 8; ++i) {
      unsigned short hi = f2bf(h[i]);
      hl[i] = f2bf(h[i] - bf2f(hi));
    }
    *(ushort8v*)(Hl + (size_t)n * 256 + sl * 8) = hl;
  }
}

// ---------------- final: out = softmax(H[M,256] @ Wm2[8,256]^T + bm2) ----------------

__global__ __launch_bounds__(256) void k_final(const float* __restrict__ H,
                                               const float* __restrict__ Wm2,
                                               const float* __restrict__ bm2,
                                               float* __restrict__ out, int M) {
  int node = blockIdx.x * 4 + (threadIdx.x >> 6);
  int lane = threadIdx.x & 63;
  if (node >= M) return;
  int o = lane >> 3;
  int r = lane & 7;
  const float* h = H + (size_t)node * D;
  const float* w = Wm2 + (size_t)o * D;
  float p = 0.f;
  for (int k = r; k < D; k += 8) p += h[k] * w[k];
  p += __shfl_xor(p, 1);
  p += __shfl_xor(p, 2);
  p += __shfl_xor(p, 4);
  float logit = p + bm2[o];
  float m = logit;
  m = fmaxf(m, __shfl_xor(m, 8));
  m = fmaxf(m, __shfl_xor(m, 16));
  m = fmaxf(m, __shfl_xor(m, 32));
  float e = expf(logit - m);
  float s = e;
  s += __shfl_xor(s, 8);
  s += __shfl_xor(s, 16);
  s += __shfl_xor(s, 32);
  if (r == 0) out[(size_t)node * 8 + o] = e / s;
}

// ---------------- launch ----------------

extern "C" void kernel_launch(void* const* d_in, const int* in_sizes, int n_in,
                              void* d_out, int out_size, void* d_ws, size_t ws_size,
                              hipStream_t stream) {
  const float* x   = (const float*)d_in[0];
  const int*   ei  = (const int*)d_in[1];
  const float* W1l = (const float*)d_in[2];
  const float* b1  = (const float*)d_in[3];
  const float* W1r = (const float*)d_in[4];
  const float* W2l = (const float*)d_in[5];
  const float* b2  = (const float*)d_in[6];
  const float* W2r = (const float*)d_in[7];
  const float* Wm1 = (const float*)d_in[8];
  const float* bm1 = (const float*)d_in[9];
  const float* Wm2 = (const float*)d_in[10];
  const float* bm2 = (const float*)d_in[11];
  float* out = (float*)d_out;

  int M = in_sizes[0] / D;   // 50000
  int E = in_sizes[1] / 2;   // 800000
  const int* src = ei;
  const int* dst = ei + E;

  char* p = (char*)d_ws;
  auto alloc = [&](size_t bytes) {
    char* q = p;
    p += (bytes + 255) & ~(size_t)255;
    return q;
  };
  unsigned short* bh0  = (unsigned short*)alloc((size_t)M * 256 * 2);  // x/h split hi
  unsigned short* bh1  = (unsigned short*)alloc((size_t)M * 256 * 2);  // x/h split lo
  unsigned short* T1bf = (unsigned short*)alloc((size_t)M * 256 * 2);  // neighbor-path (bf16)
  float*          T2f  = (float*)alloc((size_t)M * 256 * 4);           // root-path / mlp out (f32)
  unsigned short* Wc1h = (unsigned short*)alloc(512 * 256 * 2);
  unsigned short* Wc1l = (unsigned short*)alloc(512 * 256 * 2);
  unsigned short* Wc2h = (unsigned short*)alloc(512 * 256 * 2);
  unsigned short* Wc2l = (unsigned short*)alloc(512 * 256 * 2);
  unsigned short* Wm1h = (unsigned short*)alloc(256 * 256 * 2);
  unsigned short* Wm1l = (unsigned short*)alloc(256 * 256 * 2);
  int* deg     = (int*)alloc((size_t)M * 4);
  int* row_ptr = (int*)alloc((size_t)(M + 1) * 4);
  int* cursor  = (int*)alloc((size_t)M * 4);
  int* col     = (int*)alloc((size_t)E * 4);
  int* bsum    = (int*)alloc(64 * 4);
  int* boff    = (int*)alloc(64 * 4);

  int nb = (M + 1023) / 1024;  // 49

  // CSR build
  hipMemsetAsync(deg, 0, (size_t)M * sizeof(int), stream);
  k_deg<<<dim3((E + 255) / 256), dim3(256), 0, stream>>>(dst, deg, E);
  k_bsum<<<dim3(nb), dim3(256), 0, stream>>>(deg, bsum, M);
  k_scanb<<<dim3(1), dim3(64), 0, stream>>>(bsum, boff, row_ptr, nb, M);
  k_apply<<<dim3(nb), dim3(256), 0, stream>>>(deg, boff, row_ptr, cursor, M);
  k_fill<<<dim3((E + 255) / 256), dim3(256), 0, stream>>>(src, dst, cursor, col, E);

  // split conversions
  int nx4 = M * 256 / 4;
  k_split<<<dim3((nx4 + 255) / 256), dim3(256), 0, stream>>>(x, bh0, bh1, nx4);
  int nw4 = 256 * 256 / 4;
  k_split<<<dim3((nw4 + 255) / 256), dim3(256), 0, stream>>>(W1l, Wc1h, Wc1l, nw4);
  k_split<<<dim3((nw4 + 255) / 256), dim3(256), 0, stream>>>(W1r, Wc1h + 65536, Wc1l + 65536, nw4);
  k_split<<<dim3((nw4 + 255) / 256), dim3(256), 0, stream>>>(W2l, Wc2h, Wc2l, nw4);
  k_split<<<dim3((nw4 + 255) / 256), dim3(256), 0, stream>>>(W2r, Wc2h + 65536, Wc2l + 65536, nw4);
  k_split<<<dim3((nw4 + 255) / 256), dim3(256), 0, stream>>>(Wm1, Wm1h, Wm1l, nw4);

  dim3 blk(256);
  dim3 g4((M + 127) / 128, 4);
  dim3 g2((M + 127) / 128, 2);
  int aggGrid = (M + 3) / 4;

  // Layer 1: [T1 | T2] = x @ [W1l;W1r]^T ; T2 += b1 ; h1 = relu(mean(T1)+T2) -> split into bh0/bh1
  k_gemm_mfma<<<g4, blk, 0, stream>>>(bh0, bh1, Wc1h, Wc1l, T1bf, T2f, b1, M, 256, 256, 0);
  k_agg2<<<dim3(aggGrid), blk, 0, stream>>>(T1bf, T2f, bh0, bh1, row_ptr, col, M);
  // Layer 2
  k_gemm_mfma<<<g4, blk, 0, stream>>>(bh0, bh1, Wc2h, Wc2l, T1bf, T2f, b2, M, 256, 256, 0);
  k_agg2<<<dim3(aggGrid), blk, 0, stream>>>(T1bf, T2f, bh0, bh1, row_ptr, col, M);
  // MLP layer 1: h3 = relu(h2 @ Wm1^T + bm1) -> T2f
  k_gemm_mfma<<<g2, blk, 0, stream>>>(bh0, bh1, Wm1h, Wm1l, nullptr, T2f, bm1, M, 0, 256, 1);
  // logits + softmax
  k_final<<<dim3((M + 3) / 4), blk, 0, stream>>>(T2f, Wm2, bm2, out, M);
}